// Round 7
// baseline (124.643 us; speedup 1.0000x reference)
//
#include <hip/hip_runtime.h>

// Problem constants (from reference)
constexpr int   NB         = 128;          // bins per axis
constexpr int   NCELL      = NB * NB;      // 16384 cells
constexpr float S          = 7.8125f;      // 1000/128, exact in fp32
constexpr int   NUM_NETS   = 100000;
constexpr int   NUM_NODES  = 200000;
constexpr int   NUM_MOVABLE= 180000;
constexpr int   NUM_PINS   = 400000;
constexpr float UNIT_H_CAP = 1.5f;
constexpr float UNIT_V_CAP = 1.4f;

#define TPB    1024          // net_diff block size (16 waves)
#define NDB    256           // net_diff blocks: 128 chunks x {Dx,Dy}; 1/CU
#define NET_LDS_BYTES (96*1024) // 64KB used; 96KB requested to FORCE 1 block/CU
#define NCHUNK 8             // reduce chunks == XCD count (parity = map type)
#define PAD    129           // scanxy LDS row pitch (float2), breaks bank alias

__device__ __forceinline__ float edgef(int t) { return (float)t * S; }

__device__ __forceinline__ int bin_of(float v) {
    int t = (int)floorf(v / S);
    while (edgef(t + 1) <= v) ++t;
    while (edgef(t)     >  v) --t;
    return t;
}

__device__ __forceinline__ float phi(int t, float lo, float hi) {
    return fminf(fmaxf(edgef(t), lo), hi);
}

// K1: MAP-SPLIT net scatter. Block b: chunk = b>>1 (contiguous 782-net range),
// type = b&1 (0 -> Dx map with cx=w/dy, 1 -> Dy map with cy=w/dx). Each block
// owns ONE 64 KB LDS map -> P total halves to 16.8 MB while per-CU LDS-atomic
// load is unchanged (the fitted bottleneck: divergent ds_add_f32 ~5.5 cy per
// active LANE; 12.5K lane-ops/CU ~= 28 us floor — invariant at 256 CUs).
// Pin-parallel gather (R6): one net per 4-lane group, fnp coalesced,
// bbox via 2x shfl_xor; lane l owns x-entry l of the second difference.
__global__ __launch_bounds__(TPB) void net_diff_kernel(
    const float* __restrict__ pin_pos,
    const float* __restrict__ net_weights,
    const int*   __restrict__ nps,
    const int*   __restrict__ fnp,
    float* __restrict__ P) {            // [B][NCELL]
    extern __shared__ float Dl[];       // one map, NCELL floats (64 KB used)
    const int tid = threadIdx.x;

    float4* D4 = (float4*)Dl;
    for (int i = tid; i < NCELL / 4; i += TPB) D4[i] = make_float4(0, 0, 0, 0);
    __syncthreads();

    const int nchunks = (int)(gridDim.x >> 1);
    const int chunk   = (int)(blockIdx.x >> 1);
    const int type    = (int)(blockIdx.x & 1);
    const int per = (NUM_NETS + nchunks - 1) / nchunks;   // 782 @ 128 chunks
    const int n0  = chunk * per;
    const int n1  = min(n0 + per, NUM_NETS);
    const int l   = tid & 3;       // lane within 4-lane group (pin index)
    const int g   = tid >> 2;      // group id within block
    constexpr int GP = TPB / 4;    // 256 nets per iteration

    for (int n = n0 + g; n < n1; n += GP) {
        int s = nps[n], e = nps[n + 1];
        bool ok = (e > s);
        float xmin, xmax, ymin, ymax;
        if (ok && (e - s == 4)) {
            int pin = fnp[s + l];          // coalesced across the wave
            float xv = pin_pos[pin];
            float yv = pin_pos[pin + NUM_PINS];
            xmin = xv; xmax = xv; ymin = yv; ymax = yv;
        } else {
            xmin = 1e30f; xmax = -1e30f; ymin = 1e30f; ymax = -1e30f;
            if (ok && l == 0) {            // rare/never: serial fallback
                for (int p = s; p < e; ++p) {
                    int pin = fnp[p];
                    float px = pin_pos[pin];
                    float py = pin_pos[pin + NUM_PINS];
                    xmin = fminf(xmin, px); xmax = fmaxf(xmax, px);
                    ymin = fminf(ymin, py); ymax = fmaxf(ymax, py);
                }
            }
        }
        // 4-lane group min/max reduce (xor 1, xor 2 stay inside the group)
        xmin = fminf(xmin, __shfl_xor(xmin, 1));
        xmin = fminf(xmin, __shfl_xor(xmin, 2));
        xmax = fmaxf(xmax, __shfl_xor(xmax, 1));
        xmax = fmaxf(xmax, __shfl_xor(xmax, 2));
        ymin = fminf(ymin, __shfl_xor(ymin, 1));
        ymin = fminf(ymin, __shfl_xor(ymin, 2));
        ymax = fmaxf(ymax, __shfl_xor(ymax, 1));
        ymax = fmaxf(ymax, __shfl_xor(ymax, 2));
        if (!ok) continue;

        float w  = net_weights[n];
        float dx = xmax - xmin, dy = ymax - ymin;
        float c  = (type == 0) ? ((dy > 0.f) ? w / dy : 0.f)    // map_x coeff
                               : ((dx > 0.f) ? w / dx : 0.f);   // map_y coeff
        if (c == 0.f) continue;

        // this lane's x-entry of the second difference (<=4 nonzeros)
        int ax = bin_of(xmin), bx = bin_of(xmax);
        int row; bool has;
        if      (l == 0) { row = ax;     has = true; }
        else if (l == 1) { row = ax + 1; has = true; }
        else if (l == 2) { row = bx;     has = (bx > ax + 1); }
        else             { row = bx + 1; has = (bx > ax); }
        if (!has || row >= NB) continue;
        float fi = phi(row + 1, xmin, xmax) - 2.f * phi(row, xmin, xmax)
                 + phi(row - 1, xmin, xmax);
        if (fi == 0.f) continue;

        int ay = bin_of(ymin), by = bin_of(ymax);
        #pragma unroll
        for (int j = 0; j < 4; ++j) {      // compile-time j: stays in regs
            int col; bool hj;
            if      (j == 0) { col = ay;     hj = true; }
            else if (j == 1) { col = ay + 1; hj = true; }
            else if (j == 2) { col = by;     hj = (by > ay + 1); }
            else             { col = by + 1; hj = (by > ay); }
            if (!hj || col >= NB) continue;
            float fj = phi(col + 1, ymin, ymax) - 2.f * phi(col, ymin, ymax)
                     + phi(col - 1, ymin, ymax);
            float t = fi * fj;
            if (t == 0.f) continue;
            atomicAdd(&Dl[row * NB + col], c * t);
        }
    }
    __syncthreads();

    float4* Pb = (float4*)(P + (size_t)blockIdx.x * NCELL);
    for (int i = tid; i < NCELL / 4; i += TPB) Pb[i] = D4[i];
}

// K2: XCD-affine chunked reduce over the HALVED P (16.8 MB). Grid (8, 16):
// chunk = blockIdx.x -> linear block id % 8 == chunk ~= this block's XCD;
// sums blocks b ≡ chunk (mod 8). Since type = b&1, chunk parity == map type:
// even chunks accumulate Dx partials, odd chunks Dy partials.
__global__ __launch_bounds__(256) void reduce_kernel(
    const float4* __restrict__ P,   // [B][NCELL/4]
    float4* __restrict__ Rc,        // [NCHUNK][NCELL/4]
    int B) {
    constexpr int NQ = NCELL / 4;   // 4096
    int g = blockIdx.y * 256 + threadIdx.x;          // 0..4095
    int chunk = blockIdx.x;                          // 0..7
    float4 a0 = {0,0,0,0}, a1 = {0,0,0,0}, a2 = {0,0,0,0}, a3 = {0,0,0,0};
    int b = chunk;
    for (; b + 3 * NCHUNK < B; b += 4 * NCHUNK) {
        float4 v0 = P[(size_t)(b             ) * NQ + g];
        float4 v1 = P[(size_t)(b +     NCHUNK) * NQ + g];
        float4 v2 = P[(size_t)(b + 2 * NCHUNK) * NQ + g];
        float4 v3 = P[(size_t)(b + 3 * NCHUNK) * NQ + g];
        a0.x += v0.x; a0.y += v0.y; a0.z += v0.z; a0.w += v0.w;
        a1.x += v1.x; a1.y += v1.y; a1.z += v1.z; a1.w += v1.w;
        a2.x += v2.x; a2.y += v2.y; a2.z += v2.z; a2.w += v2.w;
        a3.x += v3.x; a3.y += v3.y; a3.z += v3.z; a3.w += v3.w;
    }
    for (; b < B; b += NCHUNK) {
        float4 v = P[(size_t)b * NQ + g];
        a0.x += v.x; a0.y += v.y; a0.z += v.z; a0.w += v.w;
    }
    float4 r;
    r.x = (a0.x + a1.x) + (a2.x + a3.x);
    r.y = (a0.y + a1.y) + (a2.y + a3.y);
    r.z = (a0.z + a1.z) + (a2.z + a3.z);
    r.w = (a0.w + a1.w) + (a2.w + a3.w);
    Rc[(size_t)chunk * NQ + g] = r;
}

// K3: fused x-scan + y-scan + clip, ONE block (was two kernels + Xp buffer).
// LDS tile M[r][c] (float2 = Dx,Dy) with PAD=129 pitch: x-scan thread=col
// walks rows (reads/writes stride PAD -> banks (2(r+t))%32, 4-way max);
// y-scan thread=row walks cols. Serial scans use a REGISTER accumulator so
// the LDS reads are independent (no dependent-latency chain). Then coalesced
// util writeback by all 1024 threads.
__global__ __launch_bounds__(1024) void scanxy_kernel(
    const float* __restrict__ Rc,    // [NCHUNK][NCELL]
    float* __restrict__ util) {      // [NCELL]
    extern __shared__ float2 M[];    // [NB * PAD]
    int tid = threadIdx.x;
    for (int cell = tid; cell < NCELL; cell += 1024) {
        int r = cell >> 7, c = cell & (NB - 1);
        float vx = Rc[0 * NCELL + cell] + Rc[2 * NCELL + cell]
                 + Rc[4 * NCELL + cell] + Rc[6 * NCELL + cell];
        float vy = Rc[1 * NCELL + cell] + Rc[3 * NCELL + cell]
                 + Rc[5 * NCELL + cell] + Rc[7 * NCELL + cell];
        M[r * PAD + c] = make_float2(vx, vy);
    }
    __syncthreads();
    if (tid < NB) {                  // x-scan: inclusive prefix along rows
        int col = tid;
        float2 acc = M[col];         // r = 0
        for (int r = 1; r < NB; ++r) {
            float2 v = M[r * PAD + col];
            acc.x += v.x; acc.y += v.y;
            M[r * PAD + col] = acc;
        }
    }
    __syncthreads();
    if (tid < NB) {                  // y-scan + clip -> util (in place, .x)
        int row = tid;
        constexpr float invx = 1.f / (S * S * UNIT_H_CAP);
        constexpr float invy = 1.f / (S * S * UNIT_V_CAP);
        float2 acc = make_float2(0.f, 0.f);
        for (int c = 0; c < NB; ++c) {
            float2 v = M[row * PAD + c];
            acc.x += v.x; acc.y += v.y;
            float u = fmaxf(acc.x * invx, acc.y * invy);
            M[row * PAD + c].x = fminf(fmaxf(u, 0.5f), 2.0f);
        }
    }
    __syncthreads();
    for (int cell = tid; cell < NCELL; cell += 1024)
        util[cell] = M[(cell >> 7) * PAD + (cell & (NB - 1))].x;
}

// K4: per-movable-node area = sum over <=3x3 bins of ox*util*oy
__global__ __launch_bounds__(256) void node_kernel(
    const float* __restrict__ pos,
    const float* __restrict__ nsx,
    const float* __restrict__ nsy,
    const float* __restrict__ util,
    float* __restrict__ out) {
    int m = blockIdx.x * blockDim.x + threadIdx.x;
    if (m >= NUM_MOVABLE) return;
    float x  = pos[m];
    float y  = pos[NUM_NODES + m];
    float xh = x + nsx[m];
    float yh = y + nsy[m];
    int ax = max(0,      (int)floorf(x  / S) - 1);
    int bx = min(NB - 1, (int)floorf(xh / S) + 1);
    int ay = max(0,      (int)floorf(y  / S) - 1);
    int by = min(NB - 1, (int)floorf(yh / S) + 1);
    float acc = 0.f;
    for (int i = ax; i <= bx; ++i) {
        float ov = fminf(edgef(i + 1), xh) - fmaxf(edgef(i), x);
        if (ov <= 0.f) continue;
        float inner = 0.f;
        for (int j = ay; j <= by; ++j) {
            float ovy = fminf(edgef(j + 1), yh) - fmaxf(edgef(j), y);
            if (ovy > 0.f) inner += ovy * util[i * NB + j];
        }
        acc += ov * inner;
    }
    out[m] = acc;
}

extern "C" void kernel_launch(void* const* d_in, const int* in_sizes, int n_in,
                              void* d_out, int out_size, void* d_ws, size_t ws_size,
                              hipStream_t stream) {
    const float* pos      = (const float*)d_in[0];
    const float* pin_pos  = (const float*)d_in[1];
    const float* nsx      = (const float*)d_in[2];
    const float* nsy      = (const float*)d_in[3];
    const float* nw       = (const float*)d_in[4];
    const int*   npstart  = (const int*)d_in[5];
    const int*   fnp      = (const int*)d_in[6];
    float*       out      = (float*)d_out;

    // ws layout (floats): Rc[NCHUNK*NCELL] | util[NCELL] | P[B*NCELL]
    float* w    = (float*)d_ws;
    float* Rc   = w;                           w += NCHUNK * NCELL;
    float* util = w;                           w += NCELL;
    float* P    = w;

    size_t fixed = (size_t)(w - (float*)d_ws) * sizeof(float);
    int B = NDB;
    if (ws_size > fixed) {
        size_t fit = (ws_size - fixed) / ((size_t)NCELL * sizeof(float));
        if ((size_t)B > fit) B = (int)fit;
    } else {
        B = 2;
    }
    B &= ~1;                 // must be even (chunk x type pairing)
    if (B < 2) B = 2;

    (void)hipFuncSetAttribute((const void*)net_diff_kernel,
                              hipFuncAttributeMaxDynamicSharedMemorySize,
                              NET_LDS_BYTES);
    (void)hipFuncSetAttribute((const void*)scanxy_kernel,
                              hipFuncAttributeMaxDynamicSharedMemorySize,
                              NB * PAD * (int)sizeof(float2));

    net_diff_kernel<<<B, TPB, NET_LDS_BYTES, stream>>>(
        pin_pos, nw, npstart, fnp, P);
    {
        dim3 g(NCHUNK, NCELL / 4 / 256);   // (8,16): blockIdx.x == chunk == XCD
        reduce_kernel<<<g, 256, 0, stream>>>(
            (const float4*)P, (float4*)Rc, B);
    }
    scanxy_kernel<<<1, 1024, NB * PAD * (int)sizeof(float2), stream>>>(
        Rc, util);
    node_kernel<<<(NUM_MOVABLE + 255) / 256, 256, 0, stream>>>(
        pos, nsx, nsy, util, out);
}

// Round 8
// 115.420 us; speedup vs baseline: 1.0799x; 1.0799x over previous
//
#include <hip/hip_runtime.h>

// Problem constants (from reference)
constexpr int   NB         = 128;          // bins per axis
constexpr int   NCELL      = NB * NB;      // 16384 cells
constexpr int   NFL        = 2 * NCELL;    // [Dx | Dy] floats = 32768 (linear, in P)
constexpr float S          = 7.8125f;      // 1000/128, exact in fp32
constexpr int   NUM_NETS   = 100000;
constexpr int   NUM_NODES  = 200000;
constexpr int   NUM_MOVABLE= 180000;
constexpr int   NUM_PINS   = 400000;
constexpr float UNIT_H_CAP = 1.5f;
constexpr float UNIT_V_CAP = 1.4f;

// LDS map: PADDED row stride 129 -> bank = (row+col)%32. The 4 lanes of a
// pin-group (rows a,a+1,b,b+1 at one col) hit 4 DISTINCT banks instead of 1
// (unpadded 128-stride: bank = col%32 -> guaranteed 4-way same-bank atomics,
// invisible in SQ_LDS_BANK_CONFLICT which doesn't count DS atomics).
#define PADM   129
#define HOFF   (NB * PADM)            // Dy half offset (16512 floats)
#define NLDSF  (2 * NB * PADM)        // 33024 floats = 129 KB
#define TPB    1024  // net_diff block size (16 waves)
#define NDB    256   // net_diff blocks: 1 per CU on ALL 256 CUs
#define NCHUNK 8     // reduce chunks == XCD count (XCD-affine slice sums)

__device__ __forceinline__ float edgef(int t) { return (float)t * S; }

__device__ __forceinline__ int bin_of(float v) {
    int t = (int)floorf(v / S);
    while (edgef(t + 1) <= v) ++t;
    while (edgef(t)     >  v) --t;
    return t;
}

__device__ __forceinline__ float phi(int t, float lo, float hi) {
    return fminf(fmaxf(edgef(t), lo), hi);
}

// K1: fused PIN-PARALLEL bbox gather + LDS-private scatter into PADDED
// Dx/Dy halves + bulk writeback (padded LDS -> LINEAR P[b]).
// One net per 4-lane group: lane l loads fnp[s+l] (coalesced), bbox via
// 2x shfl_xor; lane l owns x-entry l of the second difference; <=4 y-entries
// unrolled compile-time (no runtime-indexed arrays).
__global__ __launch_bounds__(TPB) void net_diff_kernel(
    const float* __restrict__ pin_pos,
    const float* __restrict__ net_weights,
    const int*   __restrict__ nps,
    const int*   __restrict__ fnp,
    float* __restrict__ P) {            // [B][NFL] linear
    extern __shared__ float Dl[];       // [Dx NB*PADM | Dy NB*PADM]
    const int tid = threadIdx.x;

    float4* D4 = (float4*)Dl;
    for (int i = tid; i < NLDSF / 4; i += TPB) D4[i] = make_float4(0, 0, 0, 0);
    __syncthreads();

    const int per = (NUM_NETS + gridDim.x - 1) / gridDim.x;   // 391
    const int n0  = blockIdx.x * per;
    const int n1  = min(n0 + per, NUM_NETS);
    const int l   = tid & 3;       // lane within 4-lane group (pin index)
    const int g   = tid >> 2;      // group id within block
    constexpr int GP = TPB / 4;    // 256 nets per iteration

    for (int n = n0 + g; n < n1; n += GP) {
        int s = nps[n], e = nps[n + 1];
        bool ok = (e > s);
        float xmin, xmax, ymin, ymax;
        if (ok && (e - s == 4)) {
            int pin = fnp[s + l];          // coalesced across the wave
            float xv = pin_pos[pin];
            float yv = pin_pos[pin + NUM_PINS];
            xmin = xv; xmax = xv; ymin = yv; ymax = yv;
        } else {
            xmin = 1e30f; xmax = -1e30f; ymin = 1e30f; ymax = -1e30f;
            if (ok && l == 0) {            // rare/never: serial fallback
                for (int p = s; p < e; ++p) {
                    int pin = fnp[p];
                    float px = pin_pos[pin];
                    float py = pin_pos[pin + NUM_PINS];
                    xmin = fminf(xmin, px); xmax = fmaxf(xmax, px);
                    ymin = fminf(ymin, py); ymax = fmaxf(ymax, py);
                }
            }
        }
        // 4-lane group min/max reduce (xor 1, xor 2 stay inside the group)
        xmin = fminf(xmin, __shfl_xor(xmin, 1));
        xmin = fminf(xmin, __shfl_xor(xmin, 2));
        xmax = fmaxf(xmax, __shfl_xor(xmax, 1));
        xmax = fmaxf(xmax, __shfl_xor(xmax, 2));
        ymin = fminf(ymin, __shfl_xor(ymin, 1));
        ymin = fminf(ymin, __shfl_xor(ymin, 2));
        ymax = fmaxf(ymax, __shfl_xor(ymax, 1));
        ymax = fmaxf(ymax, __shfl_xor(ymax, 2));
        if (!ok) continue;

        float w  = net_weights[n];
        float dx = xmax - xmin, dy = ymax - ymin;
        float cx = (dy > 0.f) ? w / dy : 0.f;   // map_x coeff
        float cy = (dx > 0.f) ? w / dx : 0.f;   // map_y coeff
        if (cx == 0.f && cy == 0.f) continue;

        // this lane's x-entry of the second difference (<=4 nonzeros)
        int ax = bin_of(xmin), bx = bin_of(xmax);
        int row; bool has;
        if      (l == 0) { row = ax;     has = true; }
        else if (l == 1) { row = ax + 1; has = true; }
        else if (l == 2) { row = bx;     has = (bx > ax + 1); }
        else             { row = bx + 1; has = (bx > ax); }
        if (!has || row >= NB) continue;
        float fi = phi(row + 1, xmin, xmax) - 2.f * phi(row, xmin, xmax)
                 + phi(row - 1, xmin, xmax);
        if (fi == 0.f) continue;

        int ay = bin_of(ymin), by = bin_of(ymax);
        int rbase = row * PADM;
        #pragma unroll
        for (int j = 0; j < 4; ++j) {      // compile-time j: stays in regs
            int col; bool hj;
            if      (j == 0) { col = ay;     hj = true; }
            else if (j == 1) { col = ay + 1; hj = true; }
            else if (j == 2) { col = by;     hj = (by > ay + 1); }
            else             { col = by + 1; hj = (by > ay); }
            if (!hj || col >= NB) continue;
            float fj = phi(col + 1, ymin, ymax) - 2.f * phi(col, ymin, ymax)
                     + phi(col - 1, ymin, ymax);
            float t = fi * fj;
            if (t == 0.f) continue;
            if (cx != 0.f) atomicAdd(&Dl[rbase + col],        cx * t);
            if (cy != 0.f) atomicAdd(&Dl[HOFF + rbase + col], cy * t);
        }
    }
    __syncthreads();

    // padded LDS -> linear P[b][NFL]; quads never cross rows (128 % 4 == 0)
    float4* Pb = (float4*)(P + (size_t)blockIdx.x * NFL);
    for (int i = tid; i < NFL / 4; i += TPB) {
        int c0 = i * 4;
        int h  = (c0 >= NCELL) ? 1 : 0;
        int cl = c0 - h * NCELL;
        int base = h * HOFF + (cl >> 7) * PADM + (cl & (NB - 1));
        Pb[i] = make_float4(Dl[base], Dl[base + 1], Dl[base + 2], Dl[base + 3]);
    }
}

// K2: XCD-affine chunked reduce. Grid (NCHUNK=8, 32): chunk = blockIdx.x ->
// linearized block id % 8 == chunk ~= this block's XCD; sums slices
// b % 8 == chunk (heuristically the slices resident in THIS XCD's L2).
__global__ __launch_bounds__(256) void reduce_kernel(
    const float4* __restrict__ P,   // [B][NFL/4]
    float4* __restrict__ Rc,        // [NCHUNK][NFL/4]
    int B) {
    constexpr int NF4 = NFL / 4;    // 8192
    int g = blockIdx.y * blockDim.x + threadIdx.x;   // 0..8191
    int chunk = blockIdx.x;                          // 0..7
    float4 a0 = {0,0,0,0}, a1 = {0,0,0,0}, a2 = {0,0,0,0}, a3 = {0,0,0,0};
    int b = chunk;
    for (; b + 3 * NCHUNK < B; b += 4 * NCHUNK) {
        float4 v0 = P[(size_t)(b             ) * NF4 + g];
        float4 v1 = P[(size_t)(b +     NCHUNK) * NF4 + g];
        float4 v2 = P[(size_t)(b + 2 * NCHUNK) * NF4 + g];
        float4 v3 = P[(size_t)(b + 3 * NCHUNK) * NF4 + g];
        a0.x += v0.x; a0.y += v0.y; a0.z += v0.z; a0.w += v0.w;
        a1.x += v1.x; a1.y += v1.y; a1.z += v1.z; a1.w += v1.w;
        a2.x += v2.x; a2.y += v2.y; a2.z += v2.z; a2.w += v2.w;
        a3.x += v3.x; a3.y += v3.y; a3.z += v3.z; a3.w += v3.w;
    }
    for (; b < B; b += NCHUNK) {
        float4 v = P[(size_t)b * NF4 + g];
        a0.x += v.x; a0.y += v.y; a0.z += v.z; a0.w += v.w;
    }
    float4 r;
    r.x = (a0.x + a1.x) + (a2.x + a3.x);
    r.y = (a0.y + a1.y) + (a2.y + a3.y);
    r.z = (a0.z + a1.z) + (a2.z + a3.z);
    r.w = (a0.w + a1.w) + (a2.w + a3.w);
    Rc[(size_t)chunk * NF4 + g] = r;
}

// K3: x-prefix. One block per y-column; thread t = x-row. Sums the 8 chunk
// maps for both (de-interleaved) halves, LDS Hillis-Steele scan over 128 rows.
__global__ __launch_bounds__(NB) void scan_x_kernel(
    const float* __restrict__ Rc,    // [NCHUNK][2][NCELL]
    float2* __restrict__ Xp) {       // [NCELL] float2, x-prefixed
    __shared__ float2 sm[NB];
    int col = blockIdx.x;
    int t = threadIdx.x;
    int idx = t * NB + col;
    float2 v = make_float2(0.f, 0.f);
    #pragma unroll
    for (int c = 0; c < NCHUNK; ++c) {
        v.x += Rc[(size_t)c * NFL + idx];
        v.y += Rc[(size_t)c * NFL + NCELL + idx];
    }
    sm[t] = v;
    __syncthreads();
    #pragma unroll
    for (int off = 1; off < NB; off <<= 1) {
        float2 cur = sm[t];
        float2 add = (t >= off) ? sm[t - off] : make_float2(0.f, 0.f);
        __syncthreads();
        cur.x += add.x; cur.y += add.y;
        sm[t] = cur;
        __syncthreads();
    }
    Xp[idx] = sm[t];
}

// K4: y-prefix + clip -> util. One block per x-row; coalesced float2 loads.
__global__ __launch_bounds__(NB) void scan_y_kernel(
    const float2* __restrict__ Xp,   // [NCELL] float2
    float* __restrict__ util) {
    __shared__ float2 sm[NB];
    int row = blockIdx.x;
    int t = threadIdx.x;
    sm[t] = Xp[row * NB + t];
    __syncthreads();
    #pragma unroll
    for (int off = 1; off < NB; off <<= 1) {
        float2 cur = sm[t];
        float2 add = (t >= off) ? sm[t - off] : make_float2(0.f, 0.f);
        __syncthreads();
        cur.x += add.x; cur.y += add.y;
        sm[t] = cur;
        __syncthreads();
    }
    constexpr float invx = 1.f / (S * S * UNIT_H_CAP);
    constexpr float invy = 1.f / (S * S * UNIT_V_CAP);
    float2 r = sm[t];
    float u = fmaxf(r.x * invx, r.y * invy);
    util[row * NB + t] = fminf(fmaxf(u, 0.5f), 2.0f);
}

// K5: per-movable-node area = sum over <=3x3 bins of ox*util*oy
__global__ __launch_bounds__(256) void node_kernel(
    const float* __restrict__ pos,
    const float* __restrict__ nsx,
    const float* __restrict__ nsy,
    const float* __restrict__ util,
    float* __restrict__ out) {
    int m = blockIdx.x * blockDim.x + threadIdx.x;
    if (m >= NUM_MOVABLE) return;
    float x  = pos[m];
    float y  = pos[NUM_NODES + m];
    float xh = x + nsx[m];
    float yh = y + nsy[m];
    int ax = max(0,      (int)floorf(x  / S) - 1);
    int bx = min(NB - 1, (int)floorf(xh / S) + 1);
    int ay = max(0,      (int)floorf(y  / S) - 1);
    int by = min(NB - 1, (int)floorf(yh / S) + 1);
    float acc = 0.f;
    for (int i = ax; i <= bx; ++i) {
        float ov = fminf(edgef(i + 1), xh) - fmaxf(edgef(i), x);
        if (ov <= 0.f) continue;
        float inner = 0.f;
        for (int j = ay; j <= by; ++j) {
            float ovy = fminf(edgef(j + 1), yh) - fmaxf(edgef(j), y);
            if (ovy > 0.f) inner += ovy * util[i * NB + j];
        }
        acc += ov * inner;
    }
    out[m] = acc;
}

extern "C" void kernel_launch(void* const* d_in, const int* in_sizes, int n_in,
                              void* d_out, int out_size, void* d_ws, size_t ws_size,
                              hipStream_t stream) {
    const float* pos      = (const float*)d_in[0];
    const float* pin_pos  = (const float*)d_in[1];
    const float* nsx      = (const float*)d_in[2];
    const float* nsy      = (const float*)d_in[3];
    const float* nw       = (const float*)d_in[4];
    const int*   npstart  = (const int*)d_in[5];
    const int*   fnp      = (const int*)d_in[6];
    float*       out      = (float*)d_out;

    // ws layout (floats): Rc[NCHUNK*NFL] | Xp[NFL] | util[NCELL] | P[B*NFL]
    float* w    = (float*)d_ws;
    float* Rc   = w;                           w += NCHUNK * NFL;
    float* Xp   = w;                           w += NFL;
    float* util = w;                           w += NCELL;
    float* P    = w;

    size_t fixed = (size_t)(w - (float*)d_ws) * sizeof(float);
    int B = NDB;
    if (ws_size > fixed) {
        size_t fit = (ws_size - fixed) / ((size_t)NFL * sizeof(float));
        if ((size_t)B > fit) B = (int)fit;
    } else {
        B = 1;
    }
    if (B < 1) B = 1;

    (void)hipFuncSetAttribute((const void*)net_diff_kernel,
                              hipFuncAttributeMaxDynamicSharedMemorySize,
                              NLDSF * (int)sizeof(float));

    net_diff_kernel<<<B, TPB, NLDSF * sizeof(float), stream>>>(
        pin_pos, nw, npstart, fnp, P);
    {
        dim3 g(NCHUNK, NFL / 4 / 256);   // (8, 32): blockIdx.x == chunk == XCD
        reduce_kernel<<<g, 256, 0, stream>>>(
            (const float4*)P, (float4*)Rc, B);
    }
    scan_x_kernel<<<NB, NB, 0, stream>>>(Rc, (float2*)Xp);
    scan_y_kernel<<<NB, NB, 0, stream>>>((const float2*)Xp, util);
    node_kernel<<<(NUM_MOVABLE + 255) / 256, 256, 0, stream>>>(
        pos, nsx, nsy, util, out);
}